// Round 1
// baseline (534.779 us; speedup 1.0000x reference)
//
#include <hip/hip_runtime.h>

namespace {
constexpr int BB  = 2;
constexpr int HQ  = 32;
constexpr int HK  = 8;
constexpr int S   = 8192;
constexpr int D   = 128;
constexpr int HID = 128;
constexpr int BS  = 16;
constexpr int NB  = 512;
constexpr int C2D = 256;   // 2*D pooled feature dim
}

// -------------------------------------------------------------------------
// Kernel 1: fused pool_cat + per-head GEMM (pooled @ w) + RoPE
// grid: (NB/32, HQ+HK, B), block 256.
// Each block: 32 pooled rows of one (b,h). Phase1 pools 512 raw rows ->
// smem[32][256] (mean|max). Phase2: [32x256]@[256x128] with 4x4 register
// tiles (w streamed from L2, float4). Epilogue: RoPE via LDS pair exchange.
// -------------------------------------------------------------------------
__global__ __launch_bounds__(256) void pool_gemm_rope_kernel(
    const float* __restrict__ qx, const float* __restrict__ kx,
    const float* __restrict__ wqp, const float* __restrict__ wkp,
    const float* __restrict__ cosp, const float* __restrict__ sinp,
    float* __restrict__ qh, float* __restrict__ kh)
{
  constexpr int PST = 260;  // pooled LDS stride (256 + 4 pad; 16B-aligned rows)
  constexpr int RST = 132;  // rope tile stride
  __shared__ float smem[32 * PST];

  const int t  = threadIdx.x;
  const int n0 = blockIdx.x * 32;
  const int hy = blockIdx.y;
  const int b  = blockIdx.z;

  const float* x; const float* w; float* o; int H; int h;
  if (hy < HQ) { x = qx; w = wqp; o = qh; H = HQ; h = hy; }
  else         { x = kx; w = wkp; o = kh; H = HK; h = hy - HQ; }

  // ---- phase 1: pool 32 blocks x (16 rows x 128 d) -> mean|max in LDS
  const float* xb = x + (((size_t)b * H + h) * S + (size_t)n0 * BS) * D;
  for (int it = t; it < 32 * 32; it += 256) {
    const int m = it >> 5, d4 = it & 31;
    const float4* p = (const float4*)(xb + (size_t)m * BS * D) + d4;
    float4 v = p[0];
    float sx = v.x, sy = v.y, sz = v.z, sw = v.w;
    float mx = v.x, my = v.y, mz = v.z, mw = v.w;
#pragma unroll
    for (int i = 1; i < BS; ++i) {
      v = p[i * (D / 4)];
      sx += v.x; sy += v.y; sz += v.z; sw += v.w;
      mx = fmaxf(mx, v.x); my = fmaxf(my, v.y);
      mz = fmaxf(mz, v.z); mw = fmaxf(mw, v.w);
    }
    const float inv16 = 1.0f / 16.0f;
    *(float4*)&smem[m * PST + 4 * d4] =
        make_float4(sx * inv16, sy * inv16, sz * inv16, sw * inv16);
    *(float4*)&smem[m * PST + 128 + 4 * d4] = make_float4(mx, my, mz, mw);
  }
  __syncthreads();

  // ---- phase 2: GEMM [32 x 256] @ [256 x 128], thread tile 4m x 4d
  const int dt = t & 31, mt = t >> 5;
  const int d0 = dt * 4, m0 = mt * 4;
  const float* wb = w + (size_t)h * C2D * HID;
  float4 acc[4];
#pragma unroll
  for (int i = 0; i < 4; ++i) acc[i] = make_float4(0.f, 0.f, 0.f, 0.f);

  for (int c = 0; c < C2D; c += 4) {
    const float4 w0 = *(const float4*)(wb + (size_t)(c + 0) * HID + d0);
    const float4 w1 = *(const float4*)(wb + (size_t)(c + 1) * HID + d0);
    const float4 w2 = *(const float4*)(wb + (size_t)(c + 2) * HID + d0);
    const float4 w3 = *(const float4*)(wb + (size_t)(c + 3) * HID + d0);
#pragma unroll
    for (int i = 0; i < 4; ++i) {
      const float4 pv = *(const float4*)&smem[(m0 + i) * PST + c];
      acc[i].x += pv.x * w0.x + pv.y * w1.x + pv.z * w2.x + pv.w * w3.x;
      acc[i].y += pv.x * w0.y + pv.y * w1.y + pv.z * w2.y + pv.w * w3.y;
      acc[i].z += pv.x * w0.z + pv.y * w1.z + pv.z * w2.z + pv.w * w3.z;
      acc[i].w += pv.x * w0.w + pv.y * w1.w + pv.z * w2.w + pv.w * w3.w;
    }
  }
  __syncthreads();  // all pooled reads done; reuse smem for rope tile

#pragma unroll
  for (int i = 0; i < 4; ++i)
    *(float4*)&smem[(m0 + i) * RST + d0] = acc[i];
  __syncthreads();

  // ---- RoPE + store: out[d] = v[d]*cos[d] + (d<64 ? -v[d+64] : v[d-64])*sin[d]
  const float sgn = (d0 < 64) ? -1.0f : 1.0f;
#pragma unroll
  for (int i = 0; i < 4; ++i) {
    const int n = n0 + m0 + i;
    const float4 cv = *(const float4*)(cosp + ((size_t)b * NB + n) * HID + d0);
    const float4 sv = *(const float4*)(sinp + ((size_t)b * NB + n) * HID + d0);
    const float4 pr = *(const float4*)&smem[(m0 + i) * RST + (d0 ^ 64)];
    float4 ov;
    ov.x = acc[i].x * cv.x + sgn * pr.x * sv.x;
    ov.y = acc[i].y * cv.y + sgn * pr.y * sv.y;
    ov.z = acc[i].z * cv.z + sgn * pr.z * sv.z;
    ov.w = acc[i].w * cv.w + sgn * pr.w * sv.w;
    *(float4*)(o + (((size_t)b * H + h) * NB + n) * HID + d0) = ov;
  }
}

// -------------------------------------------------------------------------
// Kernel 2a: causal block attention, unnormalized exp + row sums.
// grid: (4, HQ, B) — block handles q-tile pair {x, 7-x} for load balance.
// 64x64 logit tiles, thread tile 4q x 4k (rows strided by 16 so each LDS
// instr touches 16 consecutive rows). XOR swizzle on LDS columns -> no pad,
// exactly 64KB LDS -> 2 blocks/CU, conflict-free.
// -------------------------------------------------------------------------
#define SWZ(r, d4) ((r) * 128 + ((((d4) ^ ((r) & 7))) << 2))

__global__ __launch_bounds__(256) void attn_exp_kernel(
    const float* __restrict__ qh, const float* __restrict__ kh,
    float* __restrict__ out, float* __restrict__ rinv)
{
  __shared__ float qs[64 * 128];
  __shared__ float ks[64 * 128];

  const int t = threadIdx.x;
  const int x = blockIdx.x;
  const int h = blockIdx.y;
  const int b = blockIdx.z;
  const int qg = t >> 4, kg = t & 15;
  const float scale = 0.08838834764831843f;  // 1/sqrt(128)

  const float* qbase = qh + (((size_t)b * HQ + h) * NB) * HID;
  const float* kbase = kh + (((size_t)b * HK + (h >> 2)) * NB) * HID;
  float* obase = out + (((size_t)b * HQ + h) * NB) * (size_t)NB;

  const int sq = qg & 7;
  const int sk = kg & 7;

  for (int sel = 0; sel < 2; ++sel) {
    const int qt = sel ? (7 - x) : x;
    __syncthreads();  // previous iteration's reads of qs complete
    for (int it = t; it < 64 * 32; it += 256) {
      const int r = it >> 5, d4 = it & 31;
      *(float4*)&qs[SWZ(r, d4)] =
          *(const float4*)(qbase + ((size_t)(qt * 64 + r)) * HID + 4 * d4);
    }
    float rs[4] = {0.f, 0.f, 0.f, 0.f};

    for (int kt = 0; kt <= qt; ++kt) {
      __syncthreads();  // previous tile's reads of ks (and q writes) ordered
      for (int it = t; it < 64 * 32; it += 256) {
        const int r = it >> 5, d4 = it & 31;
        *(float4*)&ks[SWZ(r, d4)] =
            *(const float4*)(kbase + ((size_t)(kt * 64 + r)) * HID + 4 * d4);
      }
      __syncthreads();

      float acc[4][4];
#pragma unroll
      for (int i = 0; i < 4; ++i)
#pragma unroll
        for (int j = 0; j < 4; ++j) acc[i][j] = 0.f;

      for (int d4 = 0; d4 < 32; ++d4) {
        const int xq = ((d4 ^ sq) << 2);
        const int xk = ((d4 ^ sk) << 2);
        float4 qv[4], kv[4];
#pragma unroll
        for (int i = 0; i < 4; ++i) qv[i] = *(const float4*)&qs[(qg + 16 * i) * 128 + xq];
#pragma unroll
        for (int j = 0; j < 4; ++j) kv[j] = *(const float4*)&ks[(kg + 16 * j) * 128 + xk];
#pragma unroll
        for (int i = 0; i < 4; ++i)
#pragma unroll
          for (int j = 0; j < 4; ++j)
            acc[i][j] += qv[i].x * kv[j].x + qv[i].y * kv[j].y +
                         qv[i].z * kv[j].z + qv[i].w * kv[j].w;
      }

      const bool diag = (kt == qt);
#pragma unroll
      for (int i = 0; i < 4; ++i) {
        const int qn = qt * 64 + qg + 16 * i;
#pragma unroll
        for (int j = 0; j < 4; ++j) {
          const int kn = kt * 64 + kg + 16 * j;
          float p = 0.0f;
          if (!diag || kn <= qn) p = __expf(acc[i][j] * scale);
          rs[i] += p;
          obase[(size_t)qn * NB + kn] = p;
        }
      }
    }

    // row sums: 16 threads (kg) share each row, consecutive lanes -> shfl
#pragma unroll
    for (int i = 0; i < 4; ++i) {
      float v = rs[i];
      v += __shfl_xor(v, 1, 64);
      v += __shfl_xor(v, 2, 64);
      v += __shfl_xor(v, 4, 64);
      v += __shfl_xor(v, 8, 64);
      if (kg == 0)
        rinv[((size_t)b * HQ + h) * NB + qt * 64 + qg + 16 * i] = 1.0f / v;
    }
  }
}

// -------------------------------------------------------------------------
// Kernel 2b: normalize valid region, zero masked region.
// grid: (NB, HQ, B), block 128 (one row of 512 = 128 float4 per block).
// -------------------------------------------------------------------------
__global__ __launch_bounds__(128) void norm_kernel(
    float* __restrict__ out, const float* __restrict__ rinv)
{
  const int qn = blockIdx.x, h = blockIdx.y, b = blockIdx.z;
  const size_t row = ((size_t)b * HQ + h) * NB + qn;
  const float inv = rinv[row];
  const int klim4 = ((qn >> 6) + 1) * 16;  // valid length in float4 units
  float4* orow = (float4*)(out + row * NB);
  const int j = threadIdx.x;
  float4 v;
  if (j < klim4) {
    v = orow[j];
    v.x *= inv; v.y *= inv; v.z *= inv; v.w *= inv;
  } else {
    v = make_float4(0.f, 0.f, 0.f, 0.f);
  }
  orow[j] = v;
}

extern "C" void kernel_launch(void* const* d_in, const int* in_sizes, int n_in,
                              void* d_out, int out_size, void* d_ws, size_t ws_size,
                              hipStream_t stream)
{
  const float* q    = (const float*)d_in[0];
  const float* k    = (const float*)d_in[1];
  // d_in[2]: attention_mask — deterministic block tril, computed inline
  const float* cosp = (const float*)d_in[3];
  const float* sinp = (const float*)d_in[4];
  const float* wq   = (const float*)d_in[5];
  const float* wk   = (const float*)d_in[6];
  float* out = (float*)d_out;

  float* qh   = (float*)d_ws;                              // 2*32*512*128 f = 16 MB
  float* kh   = qh + (size_t)BB * HQ * NB * HID;           // 2* 8*512*128 f =  4 MB
  float* rinv = kh + (size_t)BB * HK * NB * HID;           // 2*32*512     f = 128 KB

  hipLaunchKernelGGL(pool_gemm_rope_kernel, dim3(NB / 32, HQ + HK, BB), dim3(256),
                     0, stream, q, k, wq, wk, cosp, sinp, qh, kh);
  hipLaunchKernelGGL(attn_exp_kernel, dim3(4, HQ, BB), dim3(256),
                     0, stream, qh, kh, out, rinv);
  hipLaunchKernelGGL(norm_kernel, dim3(NB, HQ, BB), dim3(128),
                     0, stream, out, rinv);
}

// Round 2
// 487.176 us; speedup vs baseline: 1.0977x; 1.0977x over previous
//
#include <hip/hip_runtime.h>

namespace {
constexpr int BB  = 2;
constexpr int HQ  = 32;
constexpr int HK  = 8;
constexpr int S   = 8192;
constexpr int D   = 128;
constexpr int HID = 128;
constexpr int BS  = 16;
constexpr int NB  = 512;
constexpr int C2D = 256;   // 2*D pooled feature dim
constexpr int RW  = 256;   // bf16 row width: 128 hi | 128 lo shorts
}

typedef __attribute__((ext_vector_type(8))) short short8;
typedef __attribute__((ext_vector_type(4))) float f32x4;

__device__ inline unsigned short f2bf(float f) {
  unsigned u = __builtin_bit_cast(unsigned, f);
  unsigned r = u + 0x7fff + ((u >> 16) & 1);   // RNE
  return (unsigned short)(r >> 16);
}
__device__ inline float bf2f(unsigned short s) {
  unsigned u = ((unsigned)s) << 16;
  return __builtin_bit_cast(float, u);
}

// -------------------------------------------------------------------------
// Kernel 1: fused pool_cat + per-head GEMM + RoPE + (scale for q) + bf16
// hi/lo split emit. grid: (NB/32, HQ+HK, B), block 256.
// Output rows: 256 shorts = [128 hi | 128 lo], so MFMA fragments are
// contiguous 16B per-lane gathers.
// -------------------------------------------------------------------------
__global__ __launch_bounds__(256) void pool_gemm_rope_kernel(
    const float* __restrict__ qx, const float* __restrict__ kx,
    const float* __restrict__ wqp, const float* __restrict__ wkp,
    const float* __restrict__ cosp, const float* __restrict__ sinp,
    unsigned short* __restrict__ qhb, unsigned short* __restrict__ khb)
{
  constexpr int PST = 260;  // pooled LDS stride (256 + 4 pad)
  constexpr int RST = 132;  // rope tile stride
  __shared__ float smem[32 * PST];

  const int t  = threadIdx.x;
  const int n0 = blockIdx.x * 32;
  const int hy = blockIdx.y;
  const int b  = blockIdx.z;

  const float* x; const float* w; unsigned short* o; int H; int h; bool isq;
  if (hy < HQ) { x = qx; w = wqp; o = qhb; H = HQ; h = hy; isq = true; }
  else         { x = kx; w = wkp; o = khb; H = HK; h = hy - HQ; isq = false; }

  // ---- phase 1: pool 32 blocks x (16 rows x 128 d) -> mean|max in LDS
  const float* xb = x + (((size_t)b * H + h) * S + (size_t)n0 * BS) * D;
  for (int it = t; it < 32 * 32; it += 256) {
    const int m = it >> 5, d4 = it & 31;
    const float4* p = (const float4*)(xb + (size_t)m * BS * D) + d4;
    float4 v = p[0];
    float sx = v.x, sy = v.y, sz = v.z, sw = v.w;
    float mx = v.x, my = v.y, mz = v.z, mw = v.w;
#pragma unroll
    for (int i = 1; i < BS; ++i) {
      v = p[i * (D / 4)];
      sx += v.x; sy += v.y; sz += v.z; sw += v.w;
      mx = fmaxf(mx, v.x); my = fmaxf(my, v.y);
      mz = fmaxf(mz, v.z); mw = fmaxf(mw, v.w);
    }
    const float inv16 = 1.0f / 16.0f;
    *(float4*)&smem[m * PST + 4 * d4] =
        make_float4(sx * inv16, sy * inv16, sz * inv16, sw * inv16);
    *(float4*)&smem[m * PST + 128 + 4 * d4] = make_float4(mx, my, mz, mw);
  }
  __syncthreads();

  // ---- phase 2: GEMM [32 x 256] @ [256 x 128], thread tile 4m x 4d
  const int dt = t & 31, mt = t >> 5;
  const int d0 = dt * 4, m0 = mt * 4;
  const float* wb = w + (size_t)h * C2D * HID;
  float4 acc[4];
#pragma unroll
  for (int i = 0; i < 4; ++i) acc[i] = make_float4(0.f, 0.f, 0.f, 0.f);

  for (int c = 0; c < C2D; c += 4) {
    const float4 w0 = *(const float4*)(wb + (size_t)(c + 0) * HID + d0);
    const float4 w1 = *(const float4*)(wb + (size_t)(c + 1) * HID + d0);
    const float4 w2 = *(const float4*)(wb + (size_t)(c + 2) * HID + d0);
    const float4 w3 = *(const float4*)(wb + (size_t)(c + 3) * HID + d0);
#pragma unroll
    for (int i = 0; i < 4; ++i) {
      const float4 pv = *(const float4*)&smem[(m0 + i) * PST + c];
      acc[i].x += pv.x * w0.x + pv.y * w1.x + pv.z * w2.x + pv.w * w3.x;
      acc[i].y += pv.x * w0.y + pv.y * w1.y + pv.z * w2.y + pv.w * w3.y;
      acc[i].z += pv.x * w0.z + pv.y * w1.z + pv.z * w2.z + pv.w * w3.z;
      acc[i].w += pv.x * w0.w + pv.y * w1.w + pv.z * w2.w + pv.w * w3.w;
    }
  }
  __syncthreads();

#pragma unroll
  for (int i = 0; i < 4; ++i)
    *(float4*)&smem[(m0 + i) * RST + d0] = acc[i];
  __syncthreads();

  // ---- RoPE + scale(q only) + bf16 hi/lo split + store
  const float sgn = (d0 < 64) ? -1.0f : 1.0f;
  const float qscale = isq ? 0.08838834764831843f : 1.0f;  // 1/sqrt(128)
#pragma unroll
  for (int i = 0; i < 4; ++i) {
    const int n = n0 + m0 + i;
    const float4 cv = *(const float4*)(cosp + ((size_t)b * NB + n) * HID + d0);
    const float4 sv = *(const float4*)(sinp + ((size_t)b * NB + n) * HID + d0);
    const float4 pr = *(const float4*)&smem[(m0 + i) * RST + (d0 ^ 64)];
    float ov[4];
    ov[0] = (acc[i].x * cv.x + sgn * pr.x * sv.x) * qscale;
    ov[1] = (acc[i].y * cv.y + sgn * pr.y * sv.y) * qscale;
    ov[2] = (acc[i].z * cv.z + sgn * pr.z * sv.z) * qscale;
    ov[3] = (acc[i].w * cv.w + sgn * pr.w * sv.w) * qscale;
    ushort4 hi, lo;
    hi.x = f2bf(ov[0]); lo.x = f2bf(ov[0] - bf2f(hi.x));
    hi.y = f2bf(ov[1]); lo.y = f2bf(ov[1] - bf2f(hi.y));
    hi.z = f2bf(ov[2]); lo.z = f2bf(ov[2] - bf2f(hi.z));
    hi.w = f2bf(ov[3]); lo.w = f2bf(ov[3] - bf2f(hi.w));
    unsigned short* orow = o + (((size_t)b * H + h) * NB + n) * RW + d0;
    *(ushort4*)orow = hi;
    *(ushort4*)(orow + 128) = lo;
  }
}

// -------------------------------------------------------------------------
// Kernel 2: causal block attention via bf16 MFMA (split precision),
// fused softmax normalization. grid: (16, HQ, B), block 256 (4 waves).
// Block handles q-strip pair {x, 31-x} (16 rows each); waves split k-tiles
// mod 4. Probabilities kept in registers between exp and normalize.
// MFMA 16x16x32 layouts: A[m=lane&15][k=quad*8+j], B[n=lane&15][k=quad*8+j],
// D: col(n)=lane&15, row(m)=quad*4+reg.
// -------------------------------------------------------------------------
__global__ __launch_bounds__(256) void attn_kernel(
    const unsigned short* __restrict__ qhb,
    const unsigned short* __restrict__ khb,
    float* __restrict__ out)
{
  __shared__ float rs_lds[16];

  const int t = threadIdx.x;
  const int w = t >> 6;          // wave 0..3
  const int lane = t & 63;
  const int col = lane & 15;
  const int quad = lane >> 4;
  const int x = blockIdx.x;      // 0..15
  const int h = blockIdx.y;
  const int b = blockIdx.z;

  const unsigned short* qbase = qhb + (((size_t)b * HQ + h) * NB) * RW;
  const unsigned short* kbase = khb + (((size_t)b * HK + (h >> 2)) * NB) * RW;
  float* obase = out + (((size_t)b * HQ + h) * NB) * (size_t)NB;

  for (int ph = 0; ph < 2; ++ph) {
    const int strip = ph ? (31 - x) : x;   // q-block-16 index, 0..31

    __syncthreads();                 // protect rs_lds reads of previous phase
    if (t < 16) rs_lds[t] = 0.f;
    __syncthreads();

    // Q fragments for this strip: rows strip*16+col, hi f=0..3 then lo
    const unsigned short* qrow = qbase + (size_t)(strip * 16 + col) * RW + quad * 8;
    short8 qf[8];
#pragma unroll
    for (int f = 0; f < 4; ++f) {
      qf[f]     = *(const short8*)(qrow + f * 32);
      qf[4 + f] = *(const short8*)(qrow + f * 32 + 128);
    }

    const unsigned short* krow = kbase + (size_t)col * RW + quad * 8;
    const int n = (w <= strip) ? ((strip - w) >> 2) + 1 : 0;  // my k-tiles

    f32x4 pbuf[8];
    float rs[4] = {0.f, 0.f, 0.f, 0.f};

#pragma unroll
    for (int ti = 0; ti < 8; ++ti) {
      if (ti < n) {
        const int k16 = w + 4 * ti;
        const unsigned short* kr = krow + (size_t)k16 * 16 * RW;
        short8 kf[8];
#pragma unroll
        for (int f = 0; f < 4; ++f) {
          kf[f]     = *(const short8*)(kr + f * 32);
          kf[4 + f] = *(const short8*)(kr + f * 32 + 128);
        }
        f32x4 acc = {0.f, 0.f, 0.f, 0.f};
#pragma unroll
        for (int f = 0; f < 4; ++f) {
          acc = __builtin_amdgcn_mfma_f32_16x16x32_bf16(qf[f],     kf[f],     acc, 0, 0, 0);
          acc = __builtin_amdgcn_mfma_f32_16x16x32_bf16(qf[f],     kf[4 + f], acc, 0, 0, 0);
          acc = __builtin_amdgcn_mfma_f32_16x16x32_bf16(qf[4 + f], kf[f],     acc, 0, 0, 0);
        }
        const bool diag = (k16 == strip);
        f32x4 p;
#pragma unroll
        for (int r = 0; r < 4; ++r) {
          float v = __expf(acc[r]);
          if (diag && col > quad * 4 + r) v = 0.f;
          p[r] = v;
          rs[r] += v;
        }
        pbuf[ti] = p;
      }
    }

    // reduce row sums over the 16 col-lanes, then LDS atomic across waves
#pragma unroll
    for (int r = 0; r < 4; ++r) {
      float v = rs[r];
      v += __shfl_xor(v, 1, 64);
      v += __shfl_xor(v, 2, 64);
      v += __shfl_xor(v, 4, 64);
      v += __shfl_xor(v, 8, 64);
      if (col == 0) atomicAdd(&rs_lds[quad * 4 + r], v);
    }

    // zero-fill the masked region of this strip (block-cooperative)
    {
      const int r = t & 15;
      const float4 z = make_float4(0.f, 0.f, 0.f, 0.f);
      for (int c4 = (strip + 1) * 4 + (t >> 4); c4 < 128; c4 += 16)
        *(float4*)(obase + (size_t)(strip * 16 + r) * NB + 4 * c4) = z;
    }

    __syncthreads();

    float inv[4];
#pragma unroll
    for (int r = 0; r < 4; ++r) inv[r] = 1.0f / rs_lds[quad * 4 + r];

#pragma unroll
    for (int ti = 0; ti < 8; ++ti) {
      if (ti < n) {
        const int k16 = w + 4 * ti;
#pragma unroll
        for (int r = 0; r < 4; ++r)
          obase[(size_t)(strip * 16 + quad * 4 + r) * NB + k16 * 16 + col] =
              pbuf[ti][r] * inv[r];
      }
    }
  }
}

extern "C" void kernel_launch(void* const* d_in, const int* in_sizes, int n_in,
                              void* d_out, int out_size, void* d_ws, size_t ws_size,
                              hipStream_t stream)
{
  const float* q    = (const float*)d_in[0];
  const float* k    = (const float*)d_in[1];
  // d_in[2]: attention_mask — deterministic block tril, computed inline
  const float* cosp = (const float*)d_in[3];
  const float* sinp = (const float*)d_in[4];
  const float* wq   = (const float*)d_in[5];
  const float* wk   = (const float*)d_in[6];
  float* out = (float*)d_out;

  unsigned short* qhb = (unsigned short*)d_ws;                 // 2*32*512*256 sh = 16 MB
  unsigned short* khb = qhb + (size_t)BB * HQ * NB * RW;       // 2* 8*512*256 sh =  4 MB

  hipLaunchKernelGGL(pool_gemm_rope_kernel, dim3(NB / 32, HQ + HK, BB), dim3(256),
                     0, stream, q, k, wq, wk, cosp, sinp, qhb, khb);
  hipLaunchKernelGGL(attn_kernel, dim3(16, HQ, BB), dim3(256),
                     0, stream, qhb, khb, out);
}

// Round 3
// 480.261 us; speedup vs baseline: 1.1135x; 1.0144x over previous
//
#include <hip/hip_runtime.h>

namespace {
constexpr int BB  = 2;
constexpr int HQ  = 32;
constexpr int HK  = 8;
constexpr int S   = 8192;
constexpr int D   = 128;
constexpr int HID = 128;
constexpr int BS  = 16;
constexpr int NB  = 512;
constexpr int C2D = 256;   // 2*D pooled feature dim
constexpr int RW  = 256;   // bf16 row width: 128 hi | 128 lo shorts
constexpr int WTR = 512;   // wT row: 256 hi | 256 lo shorts
}

typedef __attribute__((ext_vector_type(8))) short short8;
typedef __attribute__((ext_vector_type(4))) float f32x4;

__device__ inline unsigned short f2bf(float f) {
  unsigned u = __builtin_bit_cast(unsigned, f);
  unsigned r = u + 0x7fff + ((u >> 16) & 1);   // RNE
  return (unsigned short)(r >> 16);
}
__device__ inline float bf2f(unsigned short s) {
  unsigned u = ((unsigned)s) << 16;
  return __builtin_bit_cast(float, u);
}

// -------------------------------------------------------------------------
// Kernel 0: transpose + hi/lo-split weights into B-fragment layout.
// wT[hy][n][k]: hy 0..39 (q heads then k heads), n = output dim (128),
// row = 256 hi shorts | 256 lo shorts over k (=c, 256).
// grid (8, 40), block 256. Tiny (~5 MB of output).
// -------------------------------------------------------------------------
__global__ __launch_bounds__(256) void wprep_kernel(
    const float* __restrict__ wq, const float* __restrict__ wk,
    unsigned short* __restrict__ wT)
{
  __shared__ float ts[32 * 33];
  const int t  = threadIdx.x;
  const int kc = blockIdx.x;   // 32-wide chunk of c
  const int hy = blockIdx.y;   // head (q: 0..31, k: 32..39)
  const float* w = (hy < HQ) ? (wq + (size_t)hy * C2D * HID)
                             : (wk + (size_t)(hy - HQ) * C2D * HID);
  for (int nc = 0; nc < 4; ++nc) {
    __syncthreads();
    {
      const int r = t >> 3, c4 = t & 7;  // 32 rows x 8 float4
      *(float4*)&ts[r * 33 + 4 * c4] =
          *(const float4*)(w + (size_t)(kc * 32 + r) * HID + nc * 32 + 4 * c4);
    }
    __syncthreads();
    {
      const int n = t >> 3, g = t & 7;   // n: 0..31, g: plane/chunk
      const int cb = 8 * (g & 3);
      short8 v;
#pragma unroll
      for (int j = 0; j < 8; ++j) {
        const float f = ts[(cb + j) * 33 + n];
        const unsigned short h = f2bf(f);
        v[j] = (short)((g < 4) ? h : f2bf(f - bf2f(h)));
      }
      unsigned short* dst = wT + ((size_t)hy * HID + nc * 32 + n) * WTR +
                            ((g < 4) ? 0 : 256) + kc * 32 + cb;
      *(short8*)dst = v;
    }
  }
}

// -------------------------------------------------------------------------
// Kernel 1: fused pool_cat + per-head GEMM (split-bf16 MFMA) + RoPE +
// (q-scale) + bf16 hi/lo emit. grid: (NB/32, HQ+HK, B), block 256.
// Phase1 pools 512 raw rows -> bf16 hi/lo A-tile in LDS (row = 256 hi |
// 256 lo shorts, stride 520 -> 16B-aligned b128 reads, 2-way banks).
// Phase2: [32x256]@[256x128] via 16x16x32 bf16 MFMA, 3 mfma per hi/lo
// k-step. Epilogue: C->LDS, RoPE pair exchange, split, store.
// -------------------------------------------------------------------------
__global__ __launch_bounds__(256) void pool_gemm_rope_kernel(
    const float* __restrict__ qx, const float* __restrict__ kx,
    const unsigned short* __restrict__ wT,
    const float* __restrict__ cosp, const float* __restrict__ sinp,
    unsigned short* __restrict__ qhb, unsigned short* __restrict__ khb)
{
  constexpr int AST = 520;  // shorts per A row (512 + 8 pad)
  constexpr int CST = 132;  // floats per C row
  __shared__ unsigned short As[32 * AST];   // 33.3 KB; reused as C (fp32)
  float* Cs = (float*)As;

  const int t  = threadIdx.x;
  const int n0 = blockIdx.x * 32;
  const int hy = blockIdx.y;
  const int b  = blockIdx.z;

  const float* x; unsigned short* o; int H; int h; bool isq;
  if (hy < HQ) { x = qx; o = qhb; H = HQ; h = hy; isq = true; }
  else         { x = kx; o = khb; H = HK; h = hy - HQ; isq = false; }

  // ---- phase 1: pool 32 blocks x (16 rows x 128 d) -> hi/lo bf16 in LDS
  const float* xb = x + (((size_t)b * H + h) * S + (size_t)n0 * BS) * D;
  for (int it = t; it < 32 * 32; it += 256) {
    const int m = it >> 5, d4 = it & 31;
    const float4* p = (const float4*)(xb + (size_t)m * BS * D) + d4;
    float4 v = p[0];
    float sx = v.x, sy = v.y, sz = v.z, sw = v.w;
    float mx = v.x, my = v.y, mz = v.z, mw = v.w;
#pragma unroll
    for (int i = 1; i < BS; ++i) {
      v = p[i * (D / 4)];
      sx += v.x; sy += v.y; sz += v.z; sw += v.w;
      mx = fmaxf(mx, v.x); my = fmaxf(my, v.y);
      mz = fmaxf(mz, v.z); mw = fmaxf(mw, v.w);
    }
    const float inv16 = 1.0f / 16.0f;
    float mn[4] = {sx * inv16, sy * inv16, sz * inv16, sw * inv16};
    float mv[4] = {mx, my, mz, mw};
    ushort4 mh, ml, xh, xl;
    mh.x = f2bf(mn[0]); ml.x = f2bf(mn[0] - bf2f(mh.x));
    mh.y = f2bf(mn[1]); ml.y = f2bf(mn[1] - bf2f(mh.y));
    mh.z = f2bf(mn[2]); ml.z = f2bf(mn[2] - bf2f(mh.z));
    mh.w = f2bf(mn[3]); ml.w = f2bf(mn[3] - bf2f(mh.w));
    xh.x = f2bf(mv[0]); xl.x = f2bf(mv[0] - bf2f(xh.x));
    xh.y = f2bf(mv[1]); xl.y = f2bf(mv[1] - bf2f(xh.y));
    xh.z = f2bf(mv[2]); xl.z = f2bf(mv[2] - bf2f(xh.z));
    xh.w = f2bf(mv[3]); xl.w = f2bf(mv[3] - bf2f(xh.w));
    unsigned short* row = &As[m * AST];
    *(ushort4*)(row + 4 * d4)       = mh;   // mean hi  (k 0..127)
    *(ushort4*)(row + 256 + 4 * d4) = ml;   // mean lo
    *(ushort4*)(row + 128 + 4 * d4) = xh;   // max hi   (k 128..255)
    *(ushort4*)(row + 384 + 4 * d4) = xl;   // max lo
  }
  __syncthreads();

  // ---- phase 2: MFMA GEMM. wave w: M-tile (w&1), N-cols (w>>1)*64..+63
  const int w    = t >> 6;
  const int lane = t & 63;
  const int col  = lane & 15;
  const int quad = lane >> 4;
  const int mtile = w & 1;
  const int nbase = (w >> 1) * 64;

  const unsigned short* arow = &As[(size_t)(mtile * 16 + col) * AST + quad * 8];
  const unsigned short* bp = wT + ((size_t)hy * HID + nbase + col) * WTR + quad * 8;

  f32x4 acc[4];
#pragma unroll
  for (int i = 0; i < 4; ++i) acc[i] = (f32x4){0.f, 0.f, 0.f, 0.f};

#pragma unroll
  for (int ks = 0; ks < 8; ++ks) {
    const short8 ahi = *(const short8*)(arow + ks * 32);
    const short8 alo = *(const short8*)(arow + 256 + ks * 32);
#pragma unroll
    for (int nt = 0; nt < 4; ++nt) {
      const short8 bhi = *(const short8*)(bp + (size_t)nt * 16 * WTR + ks * 32);
      const short8 blo = *(const short8*)(bp + (size_t)nt * 16 * WTR + 256 + ks * 32);
      acc[nt] = __builtin_amdgcn_mfma_f32_16x16x32_bf16(ahi, bhi, acc[nt], 0, 0, 0);
      acc[nt] = __builtin_amdgcn_mfma_f32_16x16x32_bf16(ahi, blo, acc[nt], 0, 0, 0);
      acc[nt] = __builtin_amdgcn_mfma_f32_16x16x32_bf16(alo, bhi, acc[nt], 0, 0, 0);
    }
  }
  __syncthreads();  // all A-reads done; reuse LDS for C

#pragma unroll
  for (int nt = 0; nt < 4; ++nt)
#pragma unroll
    for (int r = 0; r < 4; ++r)
      Cs[(size_t)(mtile * 16 + quad * 4 + r) * CST + nbase + nt * 16 + col] =
          acc[nt][r];
  __syncthreads();

  // ---- RoPE + scale(q only) + bf16 hi/lo split + store
  const int dt = t & 31, mt = t >> 5;
  const int d0 = dt * 4, m0 = mt * 4;
  const float sgn = (d0 < 64) ? -1.0f : 1.0f;
  const float qscale = isq ? 0.08838834764831843f : 1.0f;  // 1/sqrt(128)
#pragma unroll
  for (int i = 0; i < 4; ++i) {
    const int n = n0 + m0 + i;
    const float4 cv = *(const float4*)(cosp + ((size_t)b * NB + n) * HID + d0);
    const float4 sv = *(const float4*)(sinp + ((size_t)b * NB + n) * HID + d0);
    const float4 cur = *(const float4*)&Cs[(m0 + i) * CST + d0];
    const float4 pr  = *(const float4*)&Cs[(m0 + i) * CST + (d0 ^ 64)];
    float ov[4];
    ov[0] = (cur.x * cv.x + sgn * pr.x * sv.x) * qscale;
    ov[1] = (cur.y * cv.y + sgn * pr.y * sv.y) * qscale;
    ov[2] = (cur.z * cv.z + sgn * pr.z * sv.z) * qscale;
    ov[3] = (cur.w * cv.w + sgn * pr.w * sv.w) * qscale;
    ushort4 hi, lo;
    hi.x = f2bf(ov[0]); lo.x = f2bf(ov[0] - bf2f(hi.x));
    hi.y = f2bf(ov[1]); lo.y = f2bf(ov[1] - bf2f(hi.y));
    hi.z = f2bf(ov[2]); lo.z = f2bf(ov[2] - bf2f(hi.z));
    hi.w = f2bf(ov[3]); lo.w = f2bf(ov[3] - bf2f(hi.w));
    unsigned short* orow = o + (((size_t)b * H + h) * NB + n) * RW + d0;
    *(ushort4*)orow = hi;
    *(ushort4*)(orow + 128) = lo;
  }
}

// -------------------------------------------------------------------------
// Kernel 2: causal block attention via bf16 MFMA (split precision),
// fused softmax normalization. grid: (16, HQ, B), block 256 (4 waves).
// Block handles q-strip pair {x, 31-x}; waves split k-tiles mod 4.
// Probabilities kept in registers between exp and normalize.
// -------------------------------------------------------------------------
__global__ __launch_bounds__(256) void attn_kernel(
    const unsigned short* __restrict__ qhb,
    const unsigned short* __restrict__ khb,
    float* __restrict__ out)
{
  __shared__ float rs_lds[16];

  const int t = threadIdx.x;
  const int w = t >> 6;          // wave 0..3
  const int lane = t & 63;
  const int col = lane & 15;
  const int quad = lane >> 4;
  const int x = blockIdx.x;      // 0..15
  const int h = blockIdx.y;
  const int b = blockIdx.z;

  const unsigned short* qbase = qhb + (((size_t)b * HQ + h) * NB) * RW;
  const unsigned short* kbase = khb + (((size_t)b * HK + (h >> 2)) * NB) * RW;
  float* obase = out + (((size_t)b * HQ + h) * NB) * (size_t)NB;

  for (int ph = 0; ph < 2; ++ph) {
    const int strip = ph ? (31 - x) : x;   // q-block-16 index, 0..31

    __syncthreads();                 // protect rs_lds reads of previous phase
    if (t < 16) rs_lds[t] = 0.f;
    __syncthreads();

    const unsigned short* qrow = qbase + (size_t)(strip * 16 + col) * RW + quad * 8;
    short8 qf[8];
#pragma unroll
    for (int f = 0; f < 4; ++f) {
      qf[f]     = *(const short8*)(qrow + f * 32);
      qf[4 + f] = *(const short8*)(qrow + f * 32 + 128);
    }

    const unsigned short* krow = kbase + (size_t)col * RW + quad * 8;
    const int n = (w <= strip) ? ((strip - w) >> 2) + 1 : 0;  // my k-tiles

    f32x4 pbuf[8];
    float rs[4] = {0.f, 0.f, 0.f, 0.f};

#pragma unroll
    for (int ti = 0; ti < 8; ++ti) {
      if (ti < n) {
        const int k16 = w + 4 * ti;
        const unsigned short* kr = krow + (size_t)k16 * 16 * RW;
        short8 kf[8];
#pragma unroll
        for (int f = 0; f < 4; ++f) {
          kf[f]     = *(const short8*)(kr + f * 32);
          kf[4 + f] = *(const short8*)(kr + f * 32 + 128);
        }
        f32x4 acc = {0.f, 0.f, 0.f, 0.f};
#pragma unroll
        for (int f = 0; f < 4; ++f) {
          acc = __builtin_amdgcn_mfma_f32_16x16x32_bf16(qf[f],     kf[f],     acc, 0, 0, 0);
          acc = __builtin_amdgcn_mfma_f32_16x16x32_bf16(qf[f],     kf[4 + f], acc, 0, 0, 0);
          acc = __builtin_amdgcn_mfma_f32_16x16x32_bf16(qf[4 + f], kf[f],     acc, 0, 0, 0);
        }
        const bool diag = (k16 == strip);
        f32x4 p;
#pragma unroll
        for (int r = 0; r < 4; ++r) {
          float v = __expf(acc[r]);
          if (diag && col > quad * 4 + r) v = 0.f;
          p[r] = v;
          rs[r] += v;
        }
        pbuf[ti] = p;
      }
    }

#pragma unroll
    for (int r = 0; r < 4; ++r) {
      float v = rs[r];
      v += __shfl_xor(v, 1, 64);
      v += __shfl_xor(v, 2, 64);
      v += __shfl_xor(v, 4, 64);
      v += __shfl_xor(v, 8, 64);
      if (col == 0) atomicAdd(&rs_lds[quad * 4 + r], v);
    }

    // zero-fill the masked region of this strip (block-cooperative)
    {
      const int r = t & 15;
      const float4 z = make_float4(0.f, 0.f, 0.f, 0.f);
      for (int c4 = (strip + 1) * 4 + (t >> 4); c4 < 128; c4 += 16)
        *(float4*)(obase + (size_t)(strip * 16 + r) * NB + 4 * c4) = z;
    }

    __syncthreads();

    float inv[4];
#pragma unroll
    for (int r = 0; r < 4; ++r) inv[r] = 1.0f / rs_lds[quad * 4 + r];

#pragma unroll
    for (int ti = 0; ti < 8; ++ti) {
      if (ti < n) {
        const int k16 = w + 4 * ti;
#pragma unroll
        for (int r = 0; r < 4; ++r)
          obase[(size_t)(strip * 16 + quad * 4 + r) * NB + k16 * 16 + col] =
              pbuf[ti][r] * inv[r];
      }
    }
  }
}

extern "C" void kernel_launch(void* const* d_in, const int* in_sizes, int n_in,
                              void* d_out, int out_size, void* d_ws, size_t ws_size,
                              hipStream_t stream)
{
  const float* q    = (const float*)d_in[0];
  const float* k    = (const float*)d_in[1];
  // d_in[2]: attention_mask — deterministic block tril, computed inline
  const float* cosp = (const float*)d_in[3];
  const float* sinp = (const float*)d_in[4];
  const float* wq   = (const float*)d_in[5];
  const float* wk   = (const float*)d_in[6];
  float* out = (float*)d_out;

  unsigned short* qhb = (unsigned short*)d_ws;                 // 16.8 MB
  unsigned short* khb = qhb + (size_t)BB * HQ * NB * RW;       //  4.2 MB
  unsigned short* wTp = khb + (size_t)BB * HK * NB * RW;       //  5.2 MB

  hipLaunchKernelGGL(wprep_kernel, dim3(8, HQ + HK), dim3(256),
                     0, stream, wq, wk, wTp);
  hipLaunchKernelGGL(pool_gemm_rope_kernel, dim3(NB / 32, HQ + HK, BB), dim3(256),
                     0, stream, q, k, wTp, cosp, sinp, qhb, khb);
  hipLaunchKernelGGL(attn_kernel, dim3(16, HQ, BB), dim3(256),
                     0, stream, qhb, khb, out);
}

// Round 4
// 469.232 us; speedup vs baseline: 1.1397x; 1.0235x over previous
//
#include <hip/hip_runtime.h>

namespace {
constexpr int BB  = 2;
constexpr int HQ  = 32;
constexpr int HK  = 8;
constexpr int S   = 8192;
constexpr int D   = 128;
constexpr int HID = 128;
constexpr int BS  = 16;
constexpr int NB  = 512;
constexpr int C2D = 256;   // 2*D pooled feature dim
constexpr int WTR = 512;   // wT row: 256 hi | 256 lo shorts
// fragment-major qh/kh: per (b,head): 32 blk16 x [8 frag][64 lane][8 shorts]
constexpr int BLK = 4096;  // shorts per blk16 (8 KB)
}

typedef __attribute__((ext_vector_type(8))) short short8;
typedef __attribute__((ext_vector_type(4))) float f32x4;

__device__ inline unsigned short f2bf(float f) {
  unsigned u = __builtin_bit_cast(unsigned, f);
  unsigned r = u + 0x7fff + ((u >> 16) & 1);   // RNE
  return (unsigned short)(r >> 16);
}
__device__ inline float bf2f(unsigned short s) {
  unsigned u = ((unsigned)s) << 16;
  return __builtin_bit_cast(float, u);
}

// -------------------------------------------------------------------------
// Kernel 0: transpose + hi/lo-split weights into B-fragment layout for the
// pool GEMM. wT[hy][n][k]: row = 256 hi | 256 lo shorts over c (=k, 256).
// grid (8, 40), block 256.
// -------------------------------------------------------------------------
__global__ __launch_bounds__(256) void wprep_kernel(
    const float* __restrict__ wq, const float* __restrict__ wk,
    unsigned short* __restrict__ wT)
{
  __shared__ float ts[32 * 33];
  const int t  = threadIdx.x;
  const int kc = blockIdx.x;   // 32-wide chunk of c
  const int hy = blockIdx.y;   // head (q: 0..31, k: 32..39)
  const float* w = (hy < HQ) ? (wq + (size_t)hy * C2D * HID)
                             : (wk + (size_t)(hy - HQ) * C2D * HID);
  for (int nc = 0; nc < 4; ++nc) {
    __syncthreads();
    {
      const int r = t >> 3, c4 = t & 7;  // 32 rows x 8 float4
      *(float4*)&ts[r * 33 + 4 * c4] =
          *(const float4*)(w + (size_t)(kc * 32 + r) * HID + nc * 32 + 4 * c4);
    }
    __syncthreads();
    {
      const int n = t >> 3, g = t & 7;   // n: 0..31, g: plane/chunk
      const int cb = 8 * (g & 3);
      short8 v;
#pragma unroll
      for (int j = 0; j < 8; ++j) {
        const float f = ts[(cb + j) * 33 + n];
        const unsigned short h = f2bf(f);
        v[j] = (short)((g < 4) ? h : f2bf(f - bf2f(h)));
      }
      unsigned short* dst = wT + ((size_t)hy * HID + nc * 32 + n) * WTR +
                            ((g < 4) ? 0 : 256) + kc * 32 + cb;
      *(short8*)dst = v;
    }
  }
}

// -------------------------------------------------------------------------
// Kernel 1: fused pool_cat + per-head GEMM (split-bf16 MFMA) + RoPE +
// (q-scale) + fragment-major hi/lo emit. grid: (NB/32, HQ+HK, B), block 256.
// Epilogue relayouts RoPE'd rows through LDS into [blk16][frag][lane][16B]
// so attention's fragment loads are fully coalesced.
// -------------------------------------------------------------------------
__global__ __launch_bounds__(256) void pool_gemm_rope_kernel(
    const float* __restrict__ qx, const float* __restrict__ kx,
    const unsigned short* __restrict__ wT,
    const float* __restrict__ cosp, const float* __restrict__ sinp,
    unsigned short* __restrict__ qhb, unsigned short* __restrict__ khb)
{
  constexpr int AST = 520;  // shorts per A row (512 + 8 pad)
  constexpr int CST = 132;  // floats per C/O row
  __shared__ unsigned short As[32 * AST];   // 33.3 KB; reused as C then O
  float* Cs = (float*)As;

  const int t  = threadIdx.x;
  const int n0 = blockIdx.x * 32;
  const int hy = blockIdx.y;
  const int b  = blockIdx.z;

  const float* x; unsigned short* o; int H; int h; bool isq;
  if (hy < HQ) { x = qx; o = qhb; H = HQ; h = hy; isq = true; }
  else         { x = kx; o = khb; H = HK; h = hy - HQ; isq = false; }

  // ---- phase 1: pool 32 blocks x (16 rows x 128 d) -> hi/lo bf16 in LDS
  const float* xb = x + (((size_t)b * H + h) * S + (size_t)n0 * BS) * D;
  for (int it = t; it < 32 * 32; it += 256) {
    const int m = it >> 5, d4 = it & 31;
    const float4* p = (const float4*)(xb + (size_t)m * BS * D) + d4;
    float4 v = p[0];
    float sx = v.x, sy = v.y, sz = v.z, sw = v.w;
    float mx = v.x, my = v.y, mz = v.z, mw = v.w;
#pragma unroll
    for (int i = 1; i < BS; ++i) {
      v = p[i * (D / 4)];
      sx += v.x; sy += v.y; sz += v.z; sw += v.w;
      mx = fmaxf(mx, v.x); my = fmaxf(my, v.y);
      mz = fmaxf(mz, v.z); mw = fmaxf(mw, v.w);
    }
    const float inv16 = 1.0f / 16.0f;
    float mn[4] = {sx * inv16, sy * inv16, sz * inv16, sw * inv16};
    float mv[4] = {mx, my, mz, mw};
    ushort4 mh, ml, xh, xl;
    mh.x = f2bf(mn[0]); ml.x = f2bf(mn[0] - bf2f(mh.x));
    mh.y = f2bf(mn[1]); ml.y = f2bf(mn[1] - bf2f(mh.y));
    mh.z = f2bf(mn[2]); ml.z = f2bf(mn[2] - bf2f(mh.z));
    mh.w = f2bf(mn[3]); ml.w = f2bf(mn[3] - bf2f(mh.w));
    xh.x = f2bf(mv[0]); xl.x = f2bf(mv[0] - bf2f(xh.x));
    xh.y = f2bf(mv[1]); xl.y = f2bf(mv[1] - bf2f(xh.y));
    xh.z = f2bf(mv[2]); xl.z = f2bf(mv[2] - bf2f(xh.z));
    xh.w = f2bf(mv[3]); xl.w = f2bf(mv[3] - bf2f(xh.w));
    unsigned short* row = &As[m * AST];
    *(ushort4*)(row + 4 * d4)       = mh;   // mean hi  (k 0..127)
    *(ushort4*)(row + 256 + 4 * d4) = ml;   // mean lo
    *(ushort4*)(row + 128 + 4 * d4) = xh;   // max hi   (k 128..255)
    *(ushort4*)(row + 384 + 4 * d4) = xl;   // max lo
  }
  __syncthreads();

  // ---- phase 2: MFMA GEMM. wave w: M-tile (w&1), N-cols (w>>1)*64..+63
  const int w    = t >> 6;
  const int lane = t & 63;
  const int col  = lane & 15;
  const int quad = lane >> 4;
  const int mtile = w & 1;
  const int nbase = (w >> 1) * 64;

  const unsigned short* arow = &As[(size_t)(mtile * 16 + col) * AST + quad * 8];
  const unsigned short* bp = wT + ((size_t)hy * HID + nbase + col) * WTR + quad * 8;

  f32x4 acc[4];
#pragma unroll
  for (int i = 0; i < 4; ++i) acc[i] = (f32x4){0.f, 0.f, 0.f, 0.f};

#pragma unroll
  for (int ks = 0; ks < 8; ++ks) {
    const short8 ahi = *(const short8*)(arow + ks * 32);
    const short8 alo = *(const short8*)(arow + 256 + ks * 32);
#pragma unroll
    for (int nt = 0; nt < 4; ++nt) {
      const short8 bhi = *(const short8*)(bp + (size_t)nt * 16 * WTR + ks * 32);
      const short8 blo = *(const short8*)(bp + (size_t)nt * 16 * WTR + 256 + ks * 32);
      acc[nt] = __builtin_amdgcn_mfma_f32_16x16x32_bf16(ahi, bhi, acc[nt], 0, 0, 0);
      acc[nt] = __builtin_amdgcn_mfma_f32_16x16x32_bf16(ahi, blo, acc[nt], 0, 0, 0);
      acc[nt] = __builtin_amdgcn_mfma_f32_16x16x32_bf16(alo, bhi, acc[nt], 0, 0, 0);
    }
  }
  __syncthreads();  // all A-reads done; reuse LDS for C

#pragma unroll
  for (int nt = 0; nt < 4; ++nt)
#pragma unroll
    for (int r = 0; r < 4; ++r)
      Cs[(size_t)(mtile * 16 + quad * 4 + r) * CST + nbase + nt * 16 + col] =
          acc[nt][r];
  __syncthreads();

  // ---- RoPE + scale(q only), results in registers
  const int dt = t & 31, mt = t >> 5;
  const int d0 = dt * 4, m0 = mt * 4;
  const float sgn = (d0 < 64) ? -1.0f : 1.0f;
  const float qscale = isq ? 0.08838834764831843f : 1.0f;  // 1/sqrt(128)
  float4 ov[4];
#pragma unroll
  for (int i = 0; i < 4; ++i) {
    const int n = n0 + m0 + i;
    const float4 cv = *(const float4*)(cosp + ((size_t)b * NB + n) * HID + d0);
    const float4 sv = *(const float4*)(sinp + ((size_t)b * NB + n) * HID + d0);
    const float4 cur = *(const float4*)&Cs[(m0 + i) * CST + d0];
    const float4 pr  = *(const float4*)&Cs[(m0 + i) * CST + (d0 ^ 64)];
    ov[i].x = (cur.x * cv.x + sgn * pr.x * sv.x) * qscale;
    ov[i].y = (cur.y * cv.y + sgn * pr.y * sv.y) * qscale;
    ov[i].z = (cur.z * cv.z + sgn * pr.z * sv.z) * qscale;
    ov[i].w = (cur.w * cv.w + sgn * pr.w * sv.w) * qscale;
  }
  __syncthreads();   // everyone finished reading Cs
#pragma unroll
  for (int i = 0; i < 4; ++i)
    *(float4*)&Cs[(m0 + i) * CST + d0] = ov[i];   // overwrite with RoPE'd O
  __syncthreads();

  // ---- relayout: 1024 chunks of 16B -> fragment-major global
  // chunk c: blk16 = c>>9, frag fi = (c>>6)&7, lane = c&63
  // lane = quadr*16+colr holds row (blk16*16+colr), d = (fi&3)*32+quadr*8..+8
  unsigned short* obase = o + ((size_t)b * H + h) * (size_t)(32 * BLK) +
                          (size_t)(n0 >> 4) * BLK;
#pragma unroll
  for (int j = 0; j < 4; ++j) {
    const int c = t + 256 * j;
    const int k16c = c >> 9;
    const int fi   = (c >> 6) & 7;
    const int ln   = c & 63;
    const int colr = ln & 15, quadr = ln >> 4;
    const int n = k16c * 16 + colr;
    const int dstart = (fi & 3) * 32 + quadr * 8;
    const float* src = &Cs[n * CST + dstart];
    short8 outv;
    if (fi < 4) {
#pragma unroll
      for (int e = 0; e < 8; ++e) outv[e] = (short)f2bf(src[e]);
    } else {
#pragma unroll
      for (int e = 0; e < 8; ++e) {
        const float f = src[e];
        outv[e] = (short)f2bf(f - bf2f(f2bf(f)));
      }
    }
    *(short8*)(obase + (size_t)k16c * BLK + (fi * 64 + ln) * 8) = outv;
  }
}

// -------------------------------------------------------------------------
// Kernel 2: causal block attention via bf16 MFMA (split precision),
// fused softmax normalization. grid: (32, HQ, B), block 256 (4 waves).
// One q-strip (16 rows) per block; waves split k-tiles mod 4.
// Fragment loads are fully coalesced (1KB contiguous per instruction).
// 3 independent MFMA accumulator chains per tile.
// -------------------------------------------------------------------------
__global__ __launch_bounds__(256) void attn_kernel(
    const unsigned short* __restrict__ qhb,
    const unsigned short* __restrict__ khb,
    float* __restrict__ out)
{
  __shared__ float rs_lds[16];

  const int t = threadIdx.x;
  const int w = t >> 6;          // wave 0..3
  const int lane = t & 63;
  const int col = lane & 15;
  const int quad = lane >> 4;
  const int strip = blockIdx.x;  // 0..31
  const int h = blockIdx.y;
  const int b = blockIdx.z;

  const unsigned short* qfb = qhb + (((size_t)b * HQ + h) * 32 + strip) * BLK;
  const unsigned short* kfb = khb + (((size_t)b * HK + (h >> 2)) * 32) * BLK;
  float* obase = out + (((size_t)b * HQ + h) * NB) * (size_t)NB;

  if (t < 16) rs_lds[t] = 0.f;
  __syncthreads();

  short8 qf[8];
#pragma unroll
  for (int fi = 0; fi < 8; ++fi)
    qf[fi] = *(const short8*)(qfb + (fi * 64 + lane) * 8);

  const int n = (w <= strip) ? ((strip - w) >> 2) + 1 : 0;  // my k-tiles

  f32x4 pbuf[8];
  float rs[4] = {0.f, 0.f, 0.f, 0.f};

#pragma unroll
  for (int ti = 0; ti < 8; ++ti) {
    if (ti < n) {
      const int k16 = w + 4 * ti;
      const unsigned short* kp = kfb + (size_t)k16 * BLK + lane * 8;
      short8 kf[8];
#pragma unroll
      for (int fi = 0; fi < 8; ++fi)
        kf[fi] = *(const short8*)(kp + fi * 512);
      f32x4 accA = {0.f, 0.f, 0.f, 0.f};
      f32x4 accB = {0.f, 0.f, 0.f, 0.f};
      f32x4 accC = {0.f, 0.f, 0.f, 0.f};
#pragma unroll
      for (int f = 0; f < 4; ++f) {
        accA = __builtin_amdgcn_mfma_f32_16x16x32_bf16(qf[f],     kf[f],     accA, 0, 0, 0);
        accB = __builtin_amdgcn_mfma_f32_16x16x32_bf16(qf[f],     kf[4 + f], accB, 0, 0, 0);
        accC = __builtin_amdgcn_mfma_f32_16x16x32_bf16(qf[4 + f], kf[f],     accC, 0, 0, 0);
      }
      const bool diag = (k16 == strip);
      f32x4 p;
#pragma unroll
      for (int r = 0; r < 4; ++r) {
        float v = __expf(accA[r] + accB[r] + accC[r]);
        if (diag && col > quad * 4 + r) v = 0.f;
        p[r] = v;
        rs[r] += v;
      }
      pbuf[ti] = p;
    }
  }

  // reduce row sums over the 16 col-lanes, then LDS atomic across waves
#pragma unroll
  for (int r = 0; r < 4; ++r) {
    float v = rs[r];
    v += __shfl_xor(v, 1, 64);
    v += __shfl_xor(v, 2, 64);
    v += __shfl_xor(v, 4, 64);
    v += __shfl_xor(v, 8, 64);
    if (col == 0) atomicAdd(&rs_lds[quad * 4 + r], v);
  }

  // zero-fill masked region (coalesced: row slow, col fast)
  {
    const int r = t >> 4;
    const float4 z = make_float4(0.f, 0.f, 0.f, 0.f);
    for (int c4 = (strip + 1) * 4 + (t & 15); c4 < 128; c4 += 16)
      *(float4*)(obase + (size_t)(strip * 16 + r) * NB + 4 * c4) = z;
  }

  __syncthreads();

  float inv[4];
#pragma unroll
  for (int r = 0; r < 4; ++r) inv[r] = 1.0f / rs_lds[quad * 4 + r];

#pragma unroll
  for (int ti = 0; ti < 8; ++ti) {
    if (ti < n) {
      const int k16 = w + 4 * ti;
#pragma unroll
      for (int r = 0; r < 4; ++r)
        obase[(size_t)(strip * 16 + quad * 4 + r) * NB + k16 * 16 + col] =
            pbuf[ti][r] * inv[r];
    }
  }
}

extern "C" void kernel_launch(void* const* d_in, const int* in_sizes, int n_in,
                              void* d_out, int out_size, void* d_ws, size_t ws_size,
                              hipStream_t stream)
{
  const float* q    = (const float*)d_in[0];
  const float* k    = (const float*)d_in[1];
  // d_in[2]: attention_mask — deterministic block tril, computed inline
  const float* cosp = (const float*)d_in[3];
  const float* sinp = (const float*)d_in[4];
  const float* wq   = (const float*)d_in[5];
  const float* wk   = (const float*)d_in[6];
  float* out = (float*)d_out;

  unsigned short* qhb = (unsigned short*)d_ws;                    // 16.8 MB
  unsigned short* khb = qhb + (size_t)BB * HQ * 32 * BLK;         //  4.2 MB
  unsigned short* wTp = khb + (size_t)BB * HK * 32 * BLK;         //  5.2 MB

  hipLaunchKernelGGL(wprep_kernel, dim3(8, HQ + HK), dim3(256),
                     0, stream, wq, wk, wTp);
  hipLaunchKernelGGL(pool_gemm_rope_kernel, dim3(NB / 32, HQ + HK, BB), dim3(256),
                     0, stream, q, k, wTp, cosp, sinp, qhb, khb);
  hipLaunchKernelGGL(attn_kernel, dim3(32, HQ, BB), dim3(256),
                     0, stream, qhb, khb, out);
}